// Round 9
// baseline (49.535 us; speedup 1.0000x reference)
//
#include <hip/hip_runtime.h>
#include <math.h>
#include <stdint.h>

#define KCODES 512
#define DIM 64
#define NROWS (64 * 4096)     // B*S = 262144
#define BLOCK 512             // 8 waves (score kernel)
#define GROUP_ROWS 32         // rows per wave per pipeline group
#define ROWS_PER_WAVE 64      // 2 groups, pipelined
#define BM ((BLOCK / 64) * ROWS_PER_WAVE)   // 512 rows per block
#define NBLK (NROWS / BM)                   // 512 blocks = 2 per CU

#define GBLOCK 256
#define GGRID 2048
#define GCHUNKS 8             // 2048*256*8 = 4M float4 = NROWS*DIM/4

typedef __bf16 bf16x8 __attribute__((ext_vector_type(8)));
typedef float f32x4 __attribute__((ext_vector_type(4)));

typedef __attribute__((address_space(3))) uint32_t* lds_ptr_t;
typedef const __attribute__((address_space(1))) uint32_t* glb_ptr_t;

// ---------------------------------------------------------------------------
// Kernel A (prep, runs once): per code k
//   en1[k] = 1.0 + ||e_k||^2 (exact fp32)
//   ebf[k*64 + (j ^ (k&7))*8 ..] = bf16(-2 * e_k[j*8..])  (pre-swizzled, -2x)
// ---------------------------------------------------------------------------
__global__ void vq_prep_kernel(const float* __restrict__ emb,
                               float* __restrict__ en1,
                               __bf16* __restrict__ ebf) {
    int k = blockIdx.x * blockDim.x + threadIdx.x;
    if (k >= KCODES) return;
    const float4* e4 = reinterpret_cast<const float4*>(emb + k * DIM);
    float s0 = 0.f, s1 = 0.f, s2 = 0.f, s3 = 0.f;
#pragma unroll
    for (int j = 0; j < 8; ++j) {
        float4 v0 = e4[j * 2];
        float4 v1 = e4[j * 2 + 1];
        s0 = fmaf(v0.x, v0.x, s0); s1 = fmaf(v0.y, v0.y, s1);
        s2 = fmaf(v0.z, v0.z, s2); s3 = fmaf(v0.w, v0.w, s3);
        s0 = fmaf(v1.x, v1.x, s0); s1 = fmaf(v1.y, v1.y, s1);
        s2 = fmaf(v1.z, v1.z, s2); s3 = fmaf(v1.w, v1.w, s3);
        bf16x8 p;
        p[0] = (__bf16)(-2.f * v0.x); p[1] = (__bf16)(-2.f * v0.y);
        p[2] = (__bf16)(-2.f * v0.z); p[3] = (__bf16)(-2.f * v0.w);
        p[4] = (__bf16)(-2.f * v1.x); p[5] = (__bf16)(-2.f * v1.y);
        p[6] = (__bf16)(-2.f * v1.z); p[7] = (__bf16)(-2.f * v1.w);
        *reinterpret_cast<bf16x8*>(&ebf[k * DIM + (j ^ (k & 7)) * 8]) = p;
    }
    en1[k] = 1.0f + (s0 + s1) + (s2 + s3);
}

// ---------------------------------------------------------------------------
// Kernel B1 (SCORE, read-stream): pipelined MFMA scoring + packed-key argmin.
//   score_k(+1) = en1[k] + x . (-2 e_k)   (acc-init = en1, bf16 MFMA)
//   key = (as_uint(score+1) & ~511) | k ; umin; tie -> smaller k.
//   loss row-sum = (score+1) - 1 + ||x||^2  (exact xsq from fp32 regs)
// Writes ONLY bestk (u16/row) + per-block loss partial. No 64MB output write
// -> the kernel is a pure latents read stream; B2 does the write stream.
// ---------------------------------------------------------------------------
__launch_bounds__(BLOCK, 4)
__global__ void vq_score_kernel(const float* __restrict__ lat,
                                const float* __restrict__ en1,
                                const __bf16* __restrict__ ebf,
                                ushort* __restrict__ bestk,
                                float* __restrict__ partials) {
    __shared__ __align__(16) __bf16 e_lds[KCODES * DIM];  // 64 KB, swizzled
    __shared__ float en_lds[KCODES];                      // 2 KB
    __shared__ float wsum_lds[BLOCK / 64];

    const int t = threadIdx.x;
    const int lane = t & 63, wid = t >> 6;
    const int l15 = lane & 15, lq = lane >> 4;
    const int swz = l15 & 7;
    const uint32_t waverow = (uint32_t)blockIdx.x * BM + (uint32_t)wid * ROWS_PER_WAVE;

    // ---- stage E: bf16 ws -> LDS, 16B/lane, linear dest (src pre-swizzled).
#pragma unroll
    for (int i = 0; i < 8; ++i) {
        int c = t + i * BLOCK;
        __builtin_amdgcn_global_load_lds(
            (glb_ptr_t)(const void*)(ebf + c * 8),
            (lds_ptr_t)(void*)(&e_lds[c * 8]), 16, 0, 0);
    }

    float4 araw[2][2][2];   // [mf][ks][half] raw fp32 A for one group
    auto load_a = [&](int g) {
#pragma unroll
        for (int mf = 0; mf < 2; ++mf)
#pragma unroll
            for (int ks = 0; ks < 2; ++ks) {
                const float* xp = lat +
                    (waverow + (uint32_t)g * GROUP_ROWS + mf * 16 + l15) * DIM +
                    ks * 32 + lq * 8;
                araw[mf][ks][0] = reinterpret_cast<const float4*>(xp)[0];
                araw[mf][ks][1] = reinterpret_cast<const float4*>(xp)[1];
            }
    };

    load_a(0);
    en_lds[t] = en1[t];   // BLOCK == KCODES
    __syncthreads();      // E + en ready (only whole-block barrier)

    float xsq = 0.f, lsum = 0.f;
    bf16x8 afrag[2][2];
    uint32_t best[2][4];

    auto cvt_a = [&]() {
#pragma unroll
        for (int mf = 0; mf < 2; ++mf)
#pragma unroll
            for (int ks = 0; ks < 2; ++ks) {
                float4 v0 = araw[mf][ks][0], v1 = araw[mf][ks][1];
                xsq = fmaf(v0.x, v0.x, xsq); xsq = fmaf(v0.y, v0.y, xsq);
                xsq = fmaf(v0.z, v0.z, xsq); xsq = fmaf(v0.w, v0.w, xsq);
                xsq = fmaf(v1.x, v1.x, xsq); xsq = fmaf(v1.y, v1.y, xsq);
                xsq = fmaf(v1.z, v1.z, xsq); xsq = fmaf(v1.w, v1.w, xsq);
                bf16x8 a;
                a[0] = (__bf16)v0.x; a[1] = (__bf16)v0.y;
                a[2] = (__bf16)v0.z; a[3] = (__bf16)v0.w;
                a[4] = (__bf16)v1.x; a[5] = (__bf16)v1.y;
                a[6] = (__bf16)v1.z; a[7] = (__bf16)v1.w;
                afrag[mf][ks] = a;
            }
    };

    auto score = [&]() {
#pragma unroll
        for (int mf = 0; mf < 2; ++mf)
#pragma unroll
            for (int r = 0; r < 4; ++r) best[mf][r] = 0xFFFFFFFFu;
#pragma unroll 4
        for (int nf = 0; nf < 32; ++nf) {
            const int n = nf * 16 + l15;
            bf16x8 b0 = *reinterpret_cast<const bf16x8*>(
                &e_lds[n * DIM + (lq ^ swz) * 8]);
            bf16x8 b1 = *reinterpret_cast<const bf16x8*>(
                &e_lds[n * DIM + ((lq + 4) ^ swz) * 8]);
            float en = en_lds[n];
            f32x4 acc0 = {en, en, en, en};
            f32x4 acc1 = {en, en, en, en};
            acc0 = __builtin_amdgcn_mfma_f32_16x16x32_bf16(afrag[0][0], b0, acc0, 0, 0, 0);
            acc0 = __builtin_amdgcn_mfma_f32_16x16x32_bf16(afrag[0][1], b1, acc0, 0, 0, 0);
            acc1 = __builtin_amdgcn_mfma_f32_16x16x32_bf16(afrag[1][0], b0, acc1, 0, 0, 0);
            acc1 = __builtin_amdgcn_mfma_f32_16x16x32_bf16(afrag[1][1], b1, acc1, 0, 0, 0);
            const uint32_t nn = (uint32_t)n;
#pragma unroll
            for (int r = 0; r < 4; ++r) {
                uint32_t k0 = (__float_as_uint(acc0[r]) & 0xFFFFFE00u) | nn;
                uint32_t k1 = (__float_as_uint(acc1[r]) & 0xFFFFFE00u) | nn;
                best[0][r] = min(best[0][r], k0);
                best[1][r] = min(best[1][r], k1);
            }
        }
    };

    auto finish = [&](int g) {
        // butterfly umin over 16 col-lanes
#pragma unroll
        for (int off = 1; off < 16; off <<= 1) {
#pragma unroll
            for (int mf = 0; mf < 2; ++mf)
#pragma unroll
                for (int r = 0; r < 4; ++r) {
                    uint32_t o = (uint32_t)__shfl_xor((int)best[mf][r], off, 64);
                    best[mf][r] = min(best[mf][r], o);
                }
        }
        // lanes l15==0: loss terms + bestk store (ushort4 per mf, aligned)
        if (l15 == 0) {
            const uint32_t rbase = waverow + (uint32_t)g * GROUP_ROWS + lq * 4;
#pragma unroll
            for (int mf = 0; mf < 2; ++mf) {
#pragma unroll
                for (int r = 0; r < 4; ++r)
                    lsum += __uint_as_float(best[mf][r] & 0xFFFFFE00u) - 1.0f;
                ushort4 s;
                s.x = (ushort)(best[mf][0] & 511u);
                s.y = (ushort)(best[mf][1] & 511u);
                s.z = (ushort)(best[mf][2] & 511u);
                s.w = (ushort)(best[mf][3] & 511u);
                *reinterpret_cast<ushort4*>(&bestk[rbase + mf * 16]) = s;
            }
        }
    };

    // ---- pipelined main body
    cvt_a();        // waits A(g0); frees araw regs
    load_a(1);      // A(g1) HBM read flies under score(g0)
    score();
    finish(0);
    cvt_a();
    score();
    finish(1);

    lsum += xsq;

    // ---- deterministic block reduce
#pragma unroll
    for (int off = 32; off > 0; off >>= 1)
        lsum += __shfl_down(lsum, off, 64);
    if (lane == 0) wsum_lds[wid] = lsum;
    __syncthreads();
    if (t == 0) {
        float s = 0.f;
#pragma unroll
        for (int w = 0; w < BLOCK / 64; ++w) s += wsum_lds[w];
        partials[blockIdx.x] = s;
    }
}

// ---------------------------------------------------------------------------
// Kernel B2 (GATHER, write-stream): out[row] = emb[bestk[row]].
// No LDS, low VGPR, 2048 tiny blocks -> fillBuffer-shaped pure write stream.
// bestk: u16, broadcast across 16 lanes (L2); emb: 64 KB, L2-resident.
// Batched: all index loads -> all emb loads -> all stores (8 independent).
// ---------------------------------------------------------------------------
__launch_bounds__(GBLOCK, 8)
__global__ void vq_gather_kernel(const ushort* __restrict__ bestk,
                                 const float* __restrict__ emb,
                                 float* __restrict__ outq) {
    const uint32_t tid = blockIdx.x * GBLOCK + threadIdx.x;
    const uint32_t stride = GGRID * GBLOCK;   // 524288
    const float4* emb4 = reinterpret_cast<const float4*>(emb);
    float4* out4 = reinterpret_cast<float4*>(outq);

    uint32_t kk[GCHUNKS];
#pragma unroll
    for (int i = 0; i < GCHUNKS; ++i) {
        uint32_t c = tid + i * stride;
        kk[i] = bestk[c >> 4];
    }
    float4 v[GCHUNKS];
#pragma unroll
    for (int i = 0; i < GCHUNKS; ++i) {
        uint32_t c = tid + i * stride;
        v[i] = emb4[kk[i] * 16u + (c & 15u)];
    }
#pragma unroll
    for (int i = 0; i < GCHUNKS; ++i) {
        uint32_t c = tid + i * stride;
        out4[c] = v[i];
    }
}

// ---------------------------------------------------------------------------
// Kernel C: reduce partials -> vq_loss = 1.25 * mean((q-x)^2)
// ---------------------------------------------------------------------------
__global__ void vq_loss_kernel(const float* __restrict__ partials,
                               float* __restrict__ loss) {
    float s = 0.f;
    for (int i = threadIdx.x; i < NBLK; i += 256) s += partials[i];
#pragma unroll
    for (int off = 32; off > 0; off >>= 1)
        s += __shfl_down(s, off, 64);
    __shared__ float wsum[4];
    const int lane = threadIdx.x & 63;
    const int wid = threadIdx.x >> 6;
    if (lane == 0) wsum[wid] = s;
    __syncthreads();
    if (threadIdx.x == 0) {
        float tsum = 0.f;
#pragma unroll
        for (int w = 0; w < 4; ++w) tsum += wsum[w];
        loss[0] = 1.25f * (tsum / (float)((size_t)NROWS * DIM));
    }
}

// ---------------------------------------------------------------------------
extern "C" void kernel_launch(void* const* d_in, const int* in_sizes, int n_in,
                              void* d_out, int out_size, void* d_ws, size_t ws_size,
                              hipStream_t stream) {
    const float* lat = (const float*)d_in[0];   // [B,S,D] fp32
    const float* emb = (const float*)d_in[1];   // [K,D]   fp32
    float* outq = (float*)d_out;                              // output 0
    float* loss = (float*)d_out + (size_t)NROWS * DIM;        // output 1

    // ws layout (bytes): [0,2048)          en1 f32[512]
    //                    [2048, 67584)     ebf bf16[512*64] (pre-swizzled, -2x)
    //                    [67584, 69632)    partials f32[512]
    //                    [69632, 593920)   bestk u16[262144]
    float* en1 = (float*)d_ws;
    __bf16* ebf = (__bf16*)((char*)d_ws + 2048);
    float* partials = (float*)((char*)d_ws + 67584);
    ushort* bestk = (ushort*)((char*)d_ws + 69632);

    vq_prep_kernel<<<2, 256, 0, stream>>>(emb, en1, ebf);
    vq_score_kernel<<<NBLK, BLOCK, 0, stream>>>(lat, en1, ebf, bestk, partials);
    vq_gather_kernel<<<GGRID, GBLOCK, 0, stream>>>(bestk, emb, outq);
    vq_loss_kernel<<<1, 256, 0, stream>>>(partials, loss);
}

// Round 10
// 47.417 us; speedup vs baseline: 1.0447x; 1.0447x over previous
//
#include <hip/hip_runtime.h>
#include <math.h>
#include <stdint.h>

#define KCODES 512
#define DIM 64
#define NROWS (64 * 4096)     // B*S = 262144
#define BLOCK 256             // 4 waves
#define ROWS_PER_WAVE 64      // 4 mf tiles of 16 rows, ONE score loop
#define BM ((BLOCK / 64) * ROWS_PER_WAVE)   // 256 rows per block
#define NBLK (NROWS / BM)                   // 1024 blocks = 4 generations

typedef __bf16 bf16x8 __attribute__((ext_vector_type(8)));
typedef float f32x4 __attribute__((ext_vector_type(4)));

typedef __attribute__((address_space(3))) uint32_t* lds_ptr_t;
typedef const __attribute__((address_space(1))) uint32_t* glb_ptr_t;

// ---------------------------------------------------------------------------
// Kernel A (prep, runs once): per code k
//   en1[k] = 1.0 + ||e_k||^2 (exact fp32)
//   ebf[k*64 + (j ^ (k&7))*8 ..] = bf16(-2 * e_k[j*8..])  (pre-swizzled, -2x)
// ---------------------------------------------------------------------------
__global__ void vq_prep_kernel(const float* __restrict__ emb,
                               float* __restrict__ en1,
                               __bf16* __restrict__ ebf) {
    int k = blockIdx.x * blockDim.x + threadIdx.x;
    if (k >= KCODES) return;
    const float4* e4 = reinterpret_cast<const float4*>(emb + k * DIM);
    float s0 = 0.f, s1 = 0.f, s2 = 0.f, s3 = 0.f;
#pragma unroll
    for (int j = 0; j < 8; ++j) {
        float4 v0 = e4[j * 2];
        float4 v1 = e4[j * 2 + 1];
        s0 = fmaf(v0.x, v0.x, s0); s1 = fmaf(v0.y, v0.y, s1);
        s2 = fmaf(v0.z, v0.z, s2); s3 = fmaf(v0.w, v0.w, s3);
        s0 = fmaf(v1.x, v1.x, s0); s1 = fmaf(v1.y, v1.y, s1);
        s2 = fmaf(v1.z, v1.z, s2); s3 = fmaf(v1.w, v1.w, s3);
        bf16x8 p;
        p[0] = (__bf16)(-2.f * v0.x); p[1] = (__bf16)(-2.f * v0.y);
        p[2] = (__bf16)(-2.f * v0.z); p[3] = (__bf16)(-2.f * v0.w);
        p[4] = (__bf16)(-2.f * v1.x); p[5] = (__bf16)(-2.f * v1.y);
        p[6] = (__bf16)(-2.f * v1.z); p[7] = (__bf16)(-2.f * v1.w);
        *reinterpret_cast<bf16x8*>(&ebf[k * DIM + (j ^ (k & 7)) * 8]) = p;
    }
    en1[k] = 1.0f + (s0 + s1) + (s2 + s3);
}

// ---------------------------------------------------------------------------
// Kernel B: fused MFMA scoring (64 rows/wave, shared B) + packed-key argmin
//           + gather + loss.
//   score_k(+1) = en1[k] + x . (-2 e_k)   (acc-init = en1, bf16 MFMA)
//   key = (as_uint(score+1) & ~511) | k ; umin; tie -> smaller k.
//   loss row-sum = (score+1) - 1 + ||x||^2  (exact xsq from fp32 regs)
// 4 mf tiles per wave share each b0/b1 ds_read -> 8 MFMA / 2KB LDS read and
// 16 independent umin chains per nf. Grid = 4 generations of blocks: gen i's
// write-drain overlaps gen i+1's E-stage/A-read (turnover pipelining).
// ---------------------------------------------------------------------------
__launch_bounds__(BLOCK, 2)
__global__ void vq_mfma_kernel(const float* __restrict__ lat,
                               const float* __restrict__ emb,
                               const float* __restrict__ en1,
                               const __bf16* __restrict__ ebf,
                               float* __restrict__ outq,
                               float* __restrict__ partials) {
    __shared__ __align__(16) __bf16 e_lds[KCODES * DIM];  // 64 KB, swizzled
    __shared__ float en_lds[KCODES];                      // 2 KB
    __shared__ float wsum_lds[BLOCK / 64];

    const int t = threadIdx.x;
    const int lane = t & 63, wid = t >> 6;
    const int l15 = lane & 15, lq = lane >> 4;
    const int swz = l15 & 7;

    // XCD-aware bijective swizzle (1024 % 8 == 0): each XCD gets a
    // contiguous 128-block range -> contiguous lat/out regions per L2.
    const uint32_t bid = (blockIdx.x & 7) * (NBLK / 8) + (blockIdx.x >> 3);
    const uint32_t waverow = bid * BM + (uint32_t)wid * ROWS_PER_WAVE;

    // ---- stage E: bf16 ws -> LDS, 16B/lane, linear dest (src pre-swizzled).
    // 4096 chunks / 256 threads = 16 each.
#pragma unroll
    for (int i = 0; i < 16; ++i) {
        int c = t + i * BLOCK;
        __builtin_amdgcn_global_load_lds(
            (glb_ptr_t)(const void*)(ebf + c * 8),
            (lds_ptr_t)(void*)(&e_lds[c * 8]), 16, 0, 0);
    }

    // ---- A loads: 4 mf tiles x 2 ks halves, raw fp32 (16 x dwordx4 VMEM).
    float4 araw[4][2][2];
#pragma unroll
    for (int mf = 0; mf < 4; ++mf) {
#pragma unroll
        for (int ks = 0; ks < 2; ++ks) {
            const float* xp = lat +
                (waverow + mf * 16 + l15) * DIM + ks * 32 + lq * 8;
            araw[mf][ks][0] = reinterpret_cast<const float4*>(xp)[0];
            araw[mf][ks][1] = reinterpret_cast<const float4*>(xp)[1];
        }
    }
    en_lds[t] = en1[t];
    en_lds[t + BLOCK] = en1[t + BLOCK];
    __syncthreads();      // drains vmcnt: E + en + A all ready

    // ---- cvt A -> bf16 frags; exact ||x||^2 from fp32 regs
    float xsq = 0.f, lsum = 0.f;
    bf16x8 afrag[4][2];
#pragma unroll
    for (int mf = 0; mf < 4; ++mf) {
#pragma unroll
        for (int ks = 0; ks < 2; ++ks) {
            float4 v0 = araw[mf][ks][0], v1 = araw[mf][ks][1];
            xsq = fmaf(v0.x, v0.x, xsq); xsq = fmaf(v0.y, v0.y, xsq);
            xsq = fmaf(v0.z, v0.z, xsq); xsq = fmaf(v0.w, v0.w, xsq);
            xsq = fmaf(v1.x, v1.x, xsq); xsq = fmaf(v1.y, v1.y, xsq);
            xsq = fmaf(v1.z, v1.z, xsq); xsq = fmaf(v1.w, v1.w, xsq);
            bf16x8 a;
            a[0] = (__bf16)v0.x; a[1] = (__bf16)v0.y;
            a[2] = (__bf16)v0.z; a[3] = (__bf16)v0.w;
            a[4] = (__bf16)v1.x; a[5] = (__bf16)v1.y;
            a[6] = (__bf16)v1.z; a[7] = (__bf16)v1.w;
            afrag[mf][ks] = a;
        }
    }

    uint32_t best[4][4];
#pragma unroll
    for (int mf = 0; mf < 4; ++mf)
#pragma unroll
        for (int r = 0; r < 4; ++r) best[mf][r] = 0xFFFFFFFFu;

    // ---- single score loop: each b0/b1 read feeds 8 MFMAs (4 mf tiles)
#pragma unroll 4
    for (int nf = 0; nf < 32; ++nf) {
        const int n = nf * 16 + l15;
        bf16x8 b0 = *reinterpret_cast<const bf16x8*>(
            &e_lds[n * DIM + (lq ^ swz) * 8]);
        bf16x8 b1 = *reinterpret_cast<const bf16x8*>(
            &e_lds[n * DIM + ((lq + 4) ^ swz) * 8]);
        float en = en_lds[n];
        const uint32_t nn = (uint32_t)n;
#pragma unroll
        for (int mf = 0; mf < 4; ++mf) {
            f32x4 acc = {en, en, en, en};
            acc = __builtin_amdgcn_mfma_f32_16x16x32_bf16(afrag[mf][0], b0, acc, 0, 0, 0);
            acc = __builtin_amdgcn_mfma_f32_16x16x32_bf16(afrag[mf][1], b1, acc, 0, 0, 0);
#pragma unroll
            for (int r = 0; r < 4; ++r) {
                uint32_t k = (__float_as_uint(acc[r]) & 0xFFFFFE00u) | nn;
                best[mf][r] = min(best[mf][r], k);
            }
        }
    }

    // ---- cross-lane umin butterfly over the 16 col-lanes
#pragma unroll
    for (int off = 1; off < 16; off <<= 1) {
#pragma unroll
        for (int mf = 0; mf < 4; ++mf)
#pragma unroll
            for (int r = 0; r < 4; ++r) {
                uint32_t o = (uint32_t)__shfl_xor((int)best[mf][r], off, 64);
                best[mf][r] = min(best[mf][r], o);
            }
    }

    // ---- loss from keys (l15==0 lanes: one key per owned row)
    if (l15 == 0) {
#pragma unroll
        for (int mf = 0; mf < 4; ++mf)
#pragma unroll
            for (int r = 0; r < 4; ++r)
                lsum += __uint_as_float(best[mf][r] & 0xFFFFFE00u) - 1.0f;
    }

    // ---- gather + output write: lane (lq,l15) writes chunk l15 of row
    // waverow + mf*16 + lq*4 + r; emb is L2-resident.
    const float4* emb4 = reinterpret_cast<const float4*>(emb);
    float4* out4 = reinterpret_cast<float4*>(outq);
#pragma unroll
    for (int mf = 0; mf < 4; ++mf) {
#pragma unroll
        for (int r = 0; r < 4; ++r) {
            const uint32_t k = best[mf][r] & 511u;
            const uint32_t grow = waverow + mf * 16 + lq * 4 + r;
            float4 e4 = emb4[k * 16 + l15];
            out4[grow * 16 + l15] = e4;
        }
    }

    lsum += xsq;

    // ---- deterministic block reduce
#pragma unroll
    for (int off = 32; off > 0; off >>= 1)
        lsum += __shfl_down(lsum, off, 64);
    if (lane == 0) wsum_lds[wid] = lsum;
    __syncthreads();
    if (t == 0) {
        float s = 0.f;
#pragma unroll
        for (int w = 0; w < BLOCK / 64; ++w) s += wsum_lds[w];
        partials[blockIdx.x] = s;
    }
}

// ---------------------------------------------------------------------------
// Kernel C: reduce partials -> vq_loss = 1.25 * mean((q-x)^2)
// ---------------------------------------------------------------------------
__global__ void vq_loss_kernel(const float* __restrict__ partials,
                               float* __restrict__ loss) {
    float s = 0.f;
    for (int i = threadIdx.x; i < NBLK; i += 256) s += partials[i];
#pragma unroll
    for (int off = 32; off > 0; off >>= 1)
        s += __shfl_down(s, off, 64);
    __shared__ float wsum[4];
    const int lane = threadIdx.x & 63;
    const int wid = threadIdx.x >> 6;
    if (lane == 0) wsum[wid] = s;
    __syncthreads();
    if (threadIdx.x == 0) {
        float tsum = 0.f;
#pragma unroll
        for (int w = 0; w < 4; ++w) tsum += wsum[w];
        loss[0] = 1.25f * (tsum / (float)((size_t)NROWS * DIM));
    }
}

// ---------------------------------------------------------------------------
extern "C" void kernel_launch(void* const* d_in, const int* in_sizes, int n_in,
                              void* d_out, int out_size, void* d_ws, size_t ws_size,
                              hipStream_t stream) {
    const float* lat = (const float*)d_in[0];   // [B,S,D] fp32
    const float* emb = (const float*)d_in[1];   // [K,D]   fp32
    float* outq = (float*)d_out;                              // output 0
    float* loss = (float*)d_out + (size_t)NROWS * DIM;        // output 1

    // ws layout (bytes): [0,2048)        en1 f32[512]
    //                    [2048, 67584)   ebf bf16[512*64] (pre-swizzled, -2x)
    //                    [67584, 71680)  partials f32[1024]
    float* en1 = (float*)d_ws;
    __bf16* ebf = (__bf16*)((char*)d_ws + 2048);
    float* partials = (float*)((char*)d_ws + 67584);

    vq_prep_kernel<<<2, 256, 0, stream>>>(emb, en1, ebf);
    vq_mfma_kernel<<<NBLK, BLOCK, 0, stream>>>(lat, emb, en1, ebf, outq, partials);
    vq_loss_kernel<<<1, 256, 0, stream>>>(partials, loss);
}

// Round 11
// 41.033 us; speedup vs baseline: 1.2072x; 1.1556x over previous
//
#include <hip/hip_runtime.h>
#include <math.h>
#include <stdint.h>

#define KCODES 512
#define DIM 64
#define NROWS (64 * 4096)     // B*S = 262144
#define BLOCK 512             // 8 waves
#define ROWS_PER_WAVE 16      // one 16-row mf tile per wave
#define BM ((BLOCK / 64) * ROWS_PER_WAVE)   // 128 rows per block
#define NBLK (NROWS / BM)                   // 2048 blocks = 8 gens of 1, 2 of 4/CU

typedef float f32x4 __attribute__((ext_vector_type(4)));
typedef long long i64t;

typedef __attribute__((address_space(3))) uint32_t* lds_ptr_t;
typedef const __attribute__((address_space(1))) uint32_t* glb_ptr_t;

// ---------------------------------------------------------------------------
// Kernel A (prep, runs once): per code k
//   en512[k] = 512 * (1 + ||e_k||^2)      (exact fp32; acc-init, pre-scaled)
//   ebf8[k*64 + (j ^ (k&7))*8 ..] = fp8_e4m3(-1024 * e_k[j*8..])
// Scale -1024 = -2 * 512 lifts e (±1/512) out of fp8 subnormal range (±2,
// full mantissa). Swizzle is the 8B-chunk XOR involution the score loop's
// ds_read applies, so linear global_load_lds staging reconstructs it.
// ---------------------------------------------------------------------------
__global__ void vq_prep_kernel(const float* __restrict__ emb,
                               float* __restrict__ en512,
                               uint8_t* __restrict__ ebf8) {
    int k = blockIdx.x * blockDim.x + threadIdx.x;
    if (k >= KCODES) return;
    const float4* e4 = reinterpret_cast<const float4*>(emb + k * DIM);
    float s0 = 0.f, s1 = 0.f, s2 = 0.f, s3 = 0.f;
#pragma unroll
    for (int j = 0; j < 8; ++j) {          // 8 chunks of 8 elems
        float4 v0 = e4[j * 2];
        float4 v1 = e4[j * 2 + 1];
        s0 = fmaf(v0.x, v0.x, s0); s1 = fmaf(v0.y, v0.y, s1);
        s2 = fmaf(v0.z, v0.z, s2); s3 = fmaf(v0.w, v0.w, s3);
        s0 = fmaf(v1.x, v1.x, s0); s1 = fmaf(v1.y, v1.y, s1);
        s2 = fmaf(v1.z, v1.z, s2); s3 = fmaf(v1.w, v1.w, s3);
        uint32_t lo = 0, hi = 0;
        lo = __builtin_amdgcn_cvt_pk_fp8_f32(-1024.f * v0.x, -1024.f * v0.y, lo, false);
        lo = __builtin_amdgcn_cvt_pk_fp8_f32(-1024.f * v0.z, -1024.f * v0.w, lo, true);
        hi = __builtin_amdgcn_cvt_pk_fp8_f32(-1024.f * v1.x, -1024.f * v1.y, hi, false);
        hi = __builtin_amdgcn_cvt_pk_fp8_f32(-1024.f * v1.z, -1024.f * v1.w, hi, true);
        uint2 p; p.x = lo; p.y = hi;
        *reinterpret_cast<uint2*>(&ebf8[k * DIM + ((j ^ (k & 7)) << 3)]) = p;
    }
    en512[k] = 512.f * (1.0f + (s0 + s1) + (s2 + s3));
}

// ---------------------------------------------------------------------------
// Kernel B: fp8 MFMA scoring + packed-key argmin + per-wave gather + loss.
//   512*(score+1) = en512[k] + fp8(x) . fp8(-1024 e_k)   (acc-init = en512)
//   positive -> as_uint monotone; key = (bits & ~511) | k ; umin; ties -> min k.
//   loss row-sum = key/512 - 1 + ||x||^2 (exact xsq from fp32 regs).
// fp8 E = 32 KB LDS -> 4 blocks/CU x 8 waves = 100% occupancy cap, with
// NBLK=2048 giving 2 generations of turnover per CU (phases interleave).
// ---------------------------------------------------------------------------
__launch_bounds__(BLOCK, 8)
__global__ void vq_mfma_kernel(const float* __restrict__ lat,
                               const float* __restrict__ emb,
                               const float* __restrict__ en512,
                               const uint8_t* __restrict__ ebf8,
                               float* __restrict__ outq,
                               float* __restrict__ partials) {
    __shared__ __align__(16) uint8_t e_lds[KCODES * DIM];  // 32 KB, swizzled
    __shared__ float en_lds[KCODES];                       // 2 KB
    __shared__ float wsum_lds[BLOCK / 64];

    const int t = threadIdx.x;
    const int lane = t & 63, wid = t >> 6;
    const int l15 = lane & 15, lq = lane >> 4;
    const int swz = l15 & 7;

    // XCD-aware bijective swizzle (2048 % 8 == 0)
    const uint32_t bid = (blockIdx.x & 7) * (NBLK / 8) + (blockIdx.x >> 3);
    const uint32_t waverow = bid * BM + (uint32_t)wid * ROWS_PER_WAVE;

    // ---- stage E: fp8 ws -> LDS, 16B/lane, linear dest (src pre-swizzled).
    // 2048 chunks of 16B / 512 threads = 4 each.
#pragma unroll
    for (int i = 0; i < 4; ++i) {
        int c = t + i * BLOCK;
        __builtin_amdgcn_global_load_lds(
            (glb_ptr_t)(const void*)(ebf8 + c * 16),
            (lds_ptr_t)(void*)(&e_lds[c * 16]), 16, 0, 0);
    }

    // ---- A loads: 16 rows/wave, raw fp32 (4 x dwordx4 per lane).
    float4 araw[2][2];   // [ks][half]
#pragma unroll
    for (int ks = 0; ks < 2; ++ks) {
        const float* xp = lat + (waverow + l15) * DIM + ks * 32 + lq * 8;
        araw[ks][0] = reinterpret_cast<const float4*>(xp)[0];
        araw[ks][1] = reinterpret_cast<const float4*>(xp)[1];
    }
    en_lds[t] = en512[t];   // BLOCK == KCODES
    __syncthreads();        // vmcnt drain: E + en + A ready

    // ---- cvt A -> fp8 frags (k = 8*lq + b within each ks); exact ||x||^2
    float xsq = 0.f, lsum = 0.f;
    i64t afrag[2];
#pragma unroll
    for (int ks = 0; ks < 2; ++ks) {
        float4 v0 = araw[ks][0], v1 = araw[ks][1];
        xsq = fmaf(v0.x, v0.x, xsq); xsq = fmaf(v0.y, v0.y, xsq);
        xsq = fmaf(v0.z, v0.z, xsq); xsq = fmaf(v0.w, v0.w, xsq);
        xsq = fmaf(v1.x, v1.x, xsq); xsq = fmaf(v1.y, v1.y, xsq);
        xsq = fmaf(v1.z, v1.z, xsq); xsq = fmaf(v1.w, v1.w, xsq);
        uint32_t lo = 0, hi = 0;
        lo = __builtin_amdgcn_cvt_pk_fp8_f32(v0.x, v0.y, lo, false);
        lo = __builtin_amdgcn_cvt_pk_fp8_f32(v0.z, v0.w, lo, true);
        hi = __builtin_amdgcn_cvt_pk_fp8_f32(v1.x, v1.y, hi, false);
        hi = __builtin_amdgcn_cvt_pk_fp8_f32(v1.z, v1.w, hi, true);
        afrag[ks] = (i64t)(((uint64_t)hi << 32) | (uint64_t)lo);
    }

    uint32_t best[4];
#pragma unroll
    for (int r = 0; r < 4; ++r) best[r] = 0xFFFFFFFFu;

    // ---- score loop: 32 groups of 16 codes from resident LDS (b64 reads)
#pragma unroll 4
    for (int nf = 0; nf < 32; ++nf) {
        const int n = nf * 16 + l15;
        i64t b0 = *reinterpret_cast<const i64t*>(
            &e_lds[n * DIM + ((lq ^ swz) << 3)]);
        i64t b1 = *reinterpret_cast<const i64t*>(
            &e_lds[n * DIM + (((lq + 4) ^ swz) << 3)]);
        float en = en_lds[n];
        f32x4 acc = {en, en, en, en};
        acc = __builtin_amdgcn_mfma_f32_16x16x32_fp8_fp8(afrag[0], b0, acc, 0, 0, 0);
        acc = __builtin_amdgcn_mfma_f32_16x16x32_fp8_fp8(afrag[1], b1, acc, 0, 0, 0);
        const uint32_t nn = (uint32_t)n;
#pragma unroll
        for (int r = 0; r < 4; ++r) {
            uint32_t k = (__float_as_uint(acc[r]) & 0xFFFFFE00u) | nn;
            best[r] = min(best[r], k);
        }
    }

    // ---- cross-lane umin butterfly: ALL 16 col-lanes end with row minima
#pragma unroll
    for (int off = 1; off < 16; off <<= 1) {
#pragma unroll
        for (int r = 0; r < 4; ++r) {
            uint32_t o = (uint32_t)__shfl_xor((int)best[r], off, 64);
            best[r] = min(best[r], o);
        }
    }

    // ---- loss from keys: row-sum (q-x)^2 = key/512 - 1 + ||x||^2
    if (l15 == 0) {
#pragma unroll
        for (int r = 0; r < 4; ++r)
            lsum = fmaf(__uint_as_float(best[r] & 0xFFFFFE00u),
                        (1.f / 512.f), lsum - 1.0f);
    }

    // ---- per-wave gather: lane (lq,l15) writes chunk l15 of row
    // waverow + lq*4 + r; emb (64 KB fp32) is L2-resident.
    const float4* emb4 = reinterpret_cast<const float4*>(emb);
    float4* out4 = reinterpret_cast<float4*>(outq);
#pragma unroll
    for (int r = 0; r < 4; ++r) {
        const uint32_t k = best[r] & 511u;
        const uint32_t grow = waverow + lq * 4 + r;
        float4 e4 = emb4[k * 16 + l15];
        out4[grow * 16 + l15] = e4;
    }

    lsum += xsq;

    // ---- deterministic block reduce
#pragma unroll
    for (int off = 32; off > 0; off >>= 1)
        lsum += __shfl_down(lsum, off, 64);
    if (lane == 0) wsum_lds[wid] = lsum;
    __syncthreads();
    if (t == 0) {
        float s = 0.f;
#pragma unroll
        for (int w = 0; w < BLOCK / 64; ++w) s += wsum_lds[w];
        partials[blockIdx.x] = s;
    }
}

// ---------------------------------------------------------------------------
// Kernel C: reduce partials -> vq_loss = 1.25 * mean((q-x)^2)
// ---------------------------------------------------------------------------
__global__ void vq_loss_kernel(const float* __restrict__ partials,
                               float* __restrict__ loss) {
    float s = 0.f;
    for (int i = threadIdx.x; i < NBLK; i += 256) s += partials[i];
#pragma unroll
    for (int off = 32; off > 0; off >>= 1)
        s += __shfl_down(s, off, 64);
    __shared__ float wsum[4];
    const int lane = threadIdx.x & 63;
    const int wid = threadIdx.x >> 6;
    if (lane == 0) wsum[wid] = s;
    __syncthreads();
    if (threadIdx.x == 0) {
        float tsum = 0.f;
#pragma unroll
        for (int w = 0; w < 4; ++w) tsum += wsum[w];
        loss[0] = 1.25f * (tsum / (float)((size_t)NROWS * DIM));
    }
}

// ---------------------------------------------------------------------------
extern "C" void kernel_launch(void* const* d_in, const int* in_sizes, int n_in,
                              void* d_out, int out_size, void* d_ws, size_t ws_size,
                              hipStream_t stream) {
    const float* lat = (const float*)d_in[0];   // [B,S,D] fp32
    const float* emb = (const float*)d_in[1];   // [K,D]   fp32
    float* outq = (float*)d_out;                              // output 0
    float* loss = (float*)d_out + (size_t)NROWS * DIM;        // output 1

    // ws layout (bytes): [0,2048)        en512 f32[512]
    //                    [2048, 34816)   ebf8 fp8[512*64] (pre-swizzled, -1024x)
    //                    [34816, 43008)  partials f32[2048]
    float* en512 = (float*)d_ws;
    uint8_t* ebf8 = (uint8_t*)d_ws + 2048;
    float* partials = (float*)((char*)d_ws + 34816);

    vq_prep_kernel<<<2, 256, 0, stream>>>(emb, en512, ebf8);
    vq_mfma_kernel<<<NBLK, BLOCK, 0, stream>>>(lat, emb, en512, ebf8, outq, partials);
    vq_loss_kernel<<<1, 256, 0, stream>>>(partials, loss);
}